// Round 1
// baseline (310.036 us; speedup 1.0000x reference)
//
#include <hip/hip_runtime.h>

#define G_N 200000
#define K_N 32
#define P_N 2048
#define EPSV 1e-8f
#define MINDIST 0.1f

#define PA_BLOCKS ((G_N + 255) / 256)     // 782 blocks for the A-pass
#define TOTAL_BLOCKS (PA_BLOCKS + P_N)    // + 2048 blocks for R row-sums

__device__ __forceinline__ float wave_reduce_sum(float v) {
#pragma unroll
  for (int d = 1; d < 64; d <<= 1) v += __shfl_xor(v, d, 64);
  return v;
}

// ws layout: [0, P_N)           pred row sums of R
//            [P_N, P_N+162)     acc: W[32] Sx[32] Sy[32] Sz[32] Q[32] cov prune
__global__ __launch_bounds__(256) void fused_main(
    const float* __restrict__ A, const float* __restrict__ x,
    const float* __restrict__ wts, const float* __restrict__ R,
    float* __restrict__ pred_sum, float* __restrict__ acc)
{
  __shared__ float smem[164];
  const int tid  = threadIdx.x;
  const int lane = tid & 63;
  const int wid  = tid >> 6;

  if (blockIdx.x >= PA_BLOCKS) {
    // ------- row sum of R: one block per pixel row (800 KB streamed) -------
    const int p = blockIdx.x - PA_BLOCKS;
    const float4* row = (const float4*)(R + (size_t)p * G_N);
    float s0 = 0.f, s1 = 0.f;
    int i = tid;
    for (; i + 256 < (G_N / 4); i += 512) {   // 2-way unroll for MLP
      float4 v0 = row[i];
      float4 v1 = row[i + 256];
      s0 += (v0.x + v0.y) + (v0.z + v0.w);
      s1 += (v1.x + v1.y) + (v1.z + v1.w);
    }
    for (; i < (G_N / 4); i += 256) {
      float4 v = row[i];
      s0 += (v.x + v.y) + (v.z + v.w);
    }
    float s = wave_reduce_sum(s0 + s1);
    if (lane == 0) smem[wid] = s;
    __syncthreads();
    if (tid == 0) pred_sum[p] = (smem[0] + smem[1]) + (smem[2] + smem[3]);
    return;
  }

  // ------- A-pass: one thread per gaussian -------
  const int g = blockIdx.x * 256 + tid;
  for (int i = tid; i < 162; i += 256) smem[i] = 0.f;
  __syncthreads();

  float p[K_N];
  float covp = 0.f, prw = 0.f;
  float wg = 0.f, x0 = 0.f, x1 = 0.f, x2 = 0.f, q = 0.f;

  if (g < G_N) {
    const float4* Ar = (const float4*)(A + (size_t)g * K_N);
    float a[K_N];
#pragma unroll
    for (int j = 0; j < 8; j++) {
      float4 v = Ar[j];
      a[4 * j + 0] = v.x; a[4 * j + 1] = v.y;
      a[4 * j + 2] = v.z; a[4 * j + 3] = v.w;
    }
    float m = a[0];
#pragma unroll
    for (int k = 1; k < K_N; k++) m = fmaxf(m, a[k]);
    float s = 0.f;
#pragma unroll
    for (int k = 0; k < K_N; k++) { p[k] = __expf(a[k] - m); s += p[k]; }
    const float invs = 1.f / s;

    // top-5 via branchless sorted insertion (p[k] > 0 so init 0 is safe)
    float t0 = 0.f, t1 = 0.f, t2 = 0.f, t3 = 0.f, t4 = 0.f;
#pragma unroll
    for (int k = 0; k < K_N; k++) {
      p[k] *= invs;
      float v = p[k], mx;
      mx = fmaxf(t0, v); v = fminf(t0, v); t0 = mx;
      mx = fmaxf(t1, v); v = fminf(t1, v); t1 = mx;
      mx = fmaxf(t2, v); v = fminf(t2, v); t2 = mx;
      mx = fmaxf(t3, v); v = fminf(t3, v); t3 = mx;
      mx = fmaxf(t4, v); v = fminf(t4, v); t4 = mx;
    }
    // cov pair term, stable pairwise form: sum_{i<j}(v_i - v_j)^2
    float d01 = t0 - t1, d02 = t0 - t2, d03 = t0 - t3, d04 = t0 - t4;
    float d12 = t1 - t2, d13 = t1 - t3, d14 = t1 - t4;
    float d23 = t2 - t3, d24 = t2 - t4, d34 = t3 - t4;
    covp = d01*d01 + d02*d02 + d03*d03 + d04*d04 + d12*d12
         + d13*d13 + d14*d14 + d23*d23 + d24*d24 + d34*d34;

    wg = wts[g];
    prw = fabsf(wg);
    x0 = x[3 * g + 0]; x1 = x[3 * g + 1]; x2 = x[3 * g + 2];
    q = x0 * x0 + x1 * x1 + x2 * x2;
  } else {
#pragma unroll
    for (int k = 0; k < K_N; k++) p[k] = 0.f;
  }

  // per-cluster reductions: W, S(3), Q  (wave butterfly, lane0 -> LDS)
#pragma unroll
  for (int k = 0; k < K_N; k++) {
    float c = wg * p[k];
    float v0 = c, v1 = c * x0, v2 = c * x1, v3 = c * x2, v4 = c * q;
#pragma unroll
    for (int d = 1; d < 64; d <<= 1) {
      v0 += __shfl_xor(v0, d, 64);
      v1 += __shfl_xor(v1, d, 64);
      v2 += __shfl_xor(v2, d, 64);
      v3 += __shfl_xor(v3, d, 64);
      v4 += __shfl_xor(v4, d, 64);
    }
    if (lane == 0) {
      atomicAdd(&smem[k],       v0);
      atomicAdd(&smem[32 + k],  v1);
      atomicAdd(&smem[64 + k],  v2);
      atomicAdd(&smem[96 + k],  v3);
      atomicAdd(&smem[128 + k], v4);
    }
  }
  covp = wave_reduce_sum(covp);
  prw  = wave_reduce_sum(prw);
  if (lane == 0) {
    atomicAdd(&smem[160], covp);
    atomicAdd(&smem[161], prw);
  }
  __syncthreads();
  if (tid < 162) atomicAdd(&acc[tid], smem[tid]);
}

__global__ __launch_bounds__(256) void finalize_k(
    const float* __restrict__ pred_sum, const int* __restrict__ mask,
    const float* __restrict__ acc, float* __restrict__ out)
{
  __shared__ float sred[4];
  __shared__ float cent[K_N][3];
  const int tid  = threadIdx.x;
  const int lane = tid & 63;
  const int wid  = tid >> 6;

  // ---- render BCE over P ----
  float bce = 0.f;
  for (int i = tid; i < P_N; i += 256) {
    float pred = fminf(fmaxf(pred_sum[i], 0.f), 1.f);
    float t = (float)mask[i];
    float lp = fmaxf(logf(pred), -100.f);        // logf(0) = -inf -> clamped
    float l1 = fmaxf(log1pf(-pred), -100.f);
    bce += t * lp + (1.f - t) * l1;
  }
  bce = wave_reduce_sum(bce);
  if (lane == 0) sred[wid] = bce;
  __syncthreads();
  const float render = -((sred[0] + sred[1]) + (sred[2] + sred[3])) / (float)P_N;

  // ---- dispersion + centroids (lanes 0..31 of wave 0) ----
  float disp_v = 0.f, sep_v = 0.f;
  if (tid < K_N) {
    float W  = acc[tid];
    float Sx = acc[32 + tid], Sy = acc[64 + tid], Sz = acc[96 + tid];
    float Q  = acc[128 + tid];
    float occ = W + EPSV;
    float inv = 1.f / occ;
    float cx = Sx * inv, cy = Sy * inv, cz = Sz * inv;
    cent[tid][0] = cx; cent[tid][1] = cy; cent[tid][2] = cz;
    disp_v = (Q - 2.f * (cx * Sx + cy * Sy + cz * Sz)
              + (cx * cx + cy * cy + cz * cz) * W) * inv;
  }
  __syncthreads();

  // ---- separation: lane i handles pairs (i, j>i) ----
  if (tid < K_N) {
    for (int j = tid + 1; j < K_N; j++) {
      float dx = cent[tid][0] - cent[j][0];
      float dy = cent[tid][1] - cent[j][1];
      float dz = cent[tid][2] - cent[j][2];
      float d = sqrtf(dx * dx + dy * dy + dz * dz);
      float r = fmaxf(MINDIST - d, 0.f);
      sep_v += r * r;
    }
  }
  if (tid < 64) {
    float dsum = wave_reduce_sum(disp_v);
    float ssum = wave_reduce_sum(sep_v);
    if (tid == 0) {
      float cov   = acc[160] / (float)G_N;
      float prune = acc[161];
      out[0] = render + dsum + ssum + cov + prune;
    }
  }
}

extern "C" void kernel_launch(void* const* d_in, const int* in_sizes, int n_in,
                              void* d_out, int out_size, void* d_ws, size_t ws_size,
                              hipStream_t stream) {
  const float* A    = (const float*)d_in[0];   // (G, K)
  const float* x    = (const float*)d_in[1];   // (G, 3)
  const float* wts  = (const float*)d_in[2];   // (G,)
  const float* R    = (const float*)d_in[3];   // (P, G)
  const int*   mask = (const int*)d_in[4];     // (P,)
  float* out = (float*)d_out;

  float* ws       = (float*)d_ws;
  float* pred_sum = ws;          // P_N floats
  float* acc      = ws + P_N;    // 162 floats

  hipMemsetAsync(acc, 0, 162 * sizeof(float), stream);
  fused_main<<<TOTAL_BLOCKS, 256, 0, stream>>>(A, x, wts, R, pred_sum, acc);
  finalize_k<<<1, 256, 0, stream>>>(pred_sum, mask, acc, out);
}